// Round 11
// baseline (97.276 us; speedup 1.0000x reference)
//
#include <hip/hip_runtime.h>

#define D 16

typedef short bf16x8 __attribute__((ext_vector_type(8)));
typedef float f32x16 __attribute__((ext_vector_type(16)));
typedef float v2f __attribute__((ext_vector_type(2)));

// ---- DPP helpers (wave64), verified rounds 8-10 ----
template<int CTRL, int RMASK, bool BC>
__device__ __forceinline__ float dpp_add(float x) {
    int t = __builtin_amdgcn_update_dpp(0, __float_as_int(x), CTRL, RMASK, 0xF, BC);
    return x + __int_as_float(t);
}
__device__ __forceinline__ float wave_iscan(float x) {
    x = dpp_add<0x111, 0xF, true >(x);   // row_shr:1
    x = dpp_add<0x112, 0xF, true >(x);   // row_shr:2
    x = dpp_add<0x114, 0xF, true >(x);   // row_shr:4
    x = dpp_add<0x118, 0xF, true >(x);   // row_shr:8
    x = dpp_add<0x142, 0xA, false>(x);   // row_bcast:15
    x = dpp_add<0x143, 0xC, false>(x);   // row_bcast:31
    return x;
}

// f32 -> bf16 round-to-nearest-even
__device__ __forceinline__ short f2bf(float f) {
    unsigned u = __float_as_uint(f);
    unsigned r = u + 0x7FFFu + ((u >> 16) & 1u);
    return (short)(r >> 16);
}

// One wave per (pair,batch). Per 32-row block: 16x mfma_32x32x16_bf16 write
// (inc-1)[32][512] (f32, rot-swizzled, 0-conflict) to LDS. Scan uses the
// deferred-base form: K[m] = B + s[m]; per row
//   g = prefix(1+e), h = prefix(c),  c_m = s[m-1]*e_m + s[m] (c_0 = s[0])
//   s' = B*g + h;  W = iscan(s'[7]);  B' = 1 + W - s'[7]
// g,h are independent of B -> they overlap the previous row's iscan chain.
// (wave_shr1 eliminated: K[i][8l-1] == B_l, proven identity.)
__global__ __launch_bounds__(64, 1)
void sig_pde_kernel(const float* __restrict__ X, const float* __restrict__ Y,
                    float* __restrict__ out) {
    __shared__ float sinc[32 * 512];        // 64 KB (inc-1) block, swizzled

    const int idx  = blockIdx.x;
    const int pair = idx >> 7;              // 0: XX, 1: YY, 2: XY
    const int a    = idx & 127;
    const float* Pp = (pair == 1) ? Y : X;  // row operand (dX)
    const float* Qp = (pair == 0) ? X : Y;  // col operand (dY)
    const float* prow = Pp + (size_t)a * 512 * D;
    const float* qrow = Qp + (size_t)a * 512 * D;

    const int l  = threadIdx.x;
    const int lm = l & 31;
    const int kh = l >> 5;                  // K-half of the fragment
    const int d0 = kh * 8;                  // this lane's dim offset
    const bool lane0 = (l == 0);

    // ---- B fragments: 16 column tiles of dY, resident in registers ----
    bf16x8 Bf[16];
    #pragma unroll
    for (int n = 0; n < 16; ++n) {
        int jj = 32 * n + lm - 1;
        if (jj < 0) jj = 0;                 // col 0 garbage (masked in scan)
        const float4* y1 = (const float4*)(qrow + (size_t)(jj + 1) * D + d0);
        const float4* y0 = (const float4*)(qrow + (size_t)jj * D + d0);
        float4 h1 = y1[0], h0 = y0[0], g1 = y1[1], g0 = y0[1];
        bf16x8 f;
        f[0] = f2bf(h1.x - h0.x); f[1] = f2bf(h1.y - h0.y);
        f[2] = f2bf(h1.z - h0.z); f[3] = f2bf(h1.w - h0.w);
        f[4] = f2bf(g1.x - g0.x); f[5] = f2bf(g1.y - g0.y);
        f[6] = f2bf(g1.z - g0.z); f[7] = f2bf(g1.w - g0.w);
        Bf[n] = f;
    }

    auto loadA = [&](int b) -> bf16x8 {
        int ii = 32 * b + lm - 1;
        if (ii < 0) ii = 0;                 // row 0 garbage (never scanned)
        const float4* x1 = (const float4*)(prow + (size_t)(ii + 1) * D + d0);
        const float4* x0 = (const float4*)(prow + (size_t)ii * D + d0);
        float4 h1 = x1[0], h0 = x0[0], g1 = x1[1], g0 = x0[1];
        bf16x8 f;
        f[0] = f2bf(h1.x - h0.x); f[1] = f2bf(h1.y - h0.y);
        f[2] = f2bf(h1.z - h0.z); f[3] = f2bf(h1.w - h0.w);
        f[4] = f2bf(g1.x - g0.x); f[5] = f2bf(g1.y - g0.y);
        f[6] = f2bf(g1.z - g0.z); f[7] = f2bf(g1.w - g0.w);
        return f;
    };

    const int rot = (l >> 2) & 7;           // read-side rotation (0-conflict)
    float* wbase = sinc + kh * 2048;

    int ea4[8];
    #pragma unroll
    for (int m = 0; m < 8; ++m) ea4[m] = (8 * l + ((m + rot) & 7)) * 4;

    // ---- scan state ----
    float s[8];
    #pragma unroll
    for (int m = 0; m < 8; ++m) s[m] = 0.0f;   // K[0][j] = 1 = B + 0
    float B = 1.0f;

    v2f ghA[8], ghB[8];
    float eA[8], eB[8];

#define PREF(BUF, RB) do {                                                    \
        const char* pb_ = (const char*)sinc + (RB);                           \
        _Pragma("unroll")                                                     \
        for (int m_ = 0; m_ < 8; ++m_)                                        \
            BUF[m_] = *(const float*)(pb_ + ea4[m_]);                         \
    } while (0)

#define GHBUILD(GH, E) do {                                                   \
        float p0_ = E[0] + 1.0f;  p0_ = lane0 ? 0.0f : p0_;                   \
        float c0_ = lane0 ? 0.0f : s[0];                                      \
        GH[0][0] = p0_; GH[0][1] = c0_;                                       \
        _Pragma("unroll")                                                     \
        for (int m_ = 1; m_ < 8; ++m_) {                                      \
            v2f pc_;                                                          \
            pc_[0] = E[m_] + 1.0f;                                            \
            pc_[1] = fmaf(s[m_ - 1], E[m_], s[m_]);                          \
            GH[m_] = GH[m_ - 1] + pc_;                                        \
        }                                                                     \
    } while (0)

#define SFMA(GH) do {                                                         \
        _Pragma("unroll")                                                     \
        for (int m_ = 0; m_ < 8; ++m_)                                        \
            s[m_] = fmaf(B, GH[m_][0], GH[m_][1]);                            \
    } while (0)

// full row step: consume GHC; prefetch EP<-byte RP; build GHN from EN
#define STEPROW(GHC, EP, RP, EN, GHN) do {                                    \
        SFMA(GHC);                                                            \
        float S_ = s[7];                                                      \
        float W_ = wave_iscan(S_);      /* serial DPP chain */                \
        PREF(EP, RP);                   /* overlaps iscan */                  \
        GHBUILD(GHN, EN);               /* overlaps iscan (no W_ dep) */      \
        B = 1.0f + (W_ - S_);                                                 \
    } while (0)

#define TAILROW(GHC) do {                                                     \
        SFMA(GHC);                                                            \
        float S_ = s[7];                                                      \
        float W_ = wave_iscan(S_);                                            \
        B = 1.0f + (W_ - S_);                                                 \
    } while (0)

    bf16x8 Acur = loadA(0);

    for (int b = 0; b < 16; ++b) {
        // ---- GEMM phase: (inc-1) rows 32b..32b+31, all 512 cols ----
        #pragma unroll
        for (int n = 0; n < 16; ++n) {
            f32x16 acc = {-1.f,-1.f,-1.f,-1.f,-1.f,-1.f,-1.f,-1.f,
                          -1.f,-1.f,-1.f,-1.f,-1.f,-1.f,-1.f,-1.f};
            acc = __builtin_amdgcn_mfma_f32_32x32x16_bf16(Acur, Bf[n], acc, 0, 0, 0);
            float* p = wbase + 32 * n + (lm & ~7) + (((l & 7) + n) & 7);
            #pragma unroll
            for (int r = 0; r < 16; ++r)
                p[(r & 3) * 512 + (r >> 2) * 4096] = acc[r];
        }
        if (b < 15) Acur = loadA(b + 1);    // global prefetch under the scan

        // ---- scan phase: 32 steps (block 0: dummy step resets to s=0,B=1) --
        if (b == 0) {
            #pragma unroll
            for (int m = 0; m < 8; ++m) { ghA[m][0] = 0.0f; ghA[m][1] = 0.0f; }
            PREF(eB, 2048);                 // tile row 1 (first real row)
        } else {
            PREF(eA, 0);                    // tile row 0
            GHBUILD(ghA, eA);
            PREF(eB, 2048);                 // tile row 1
        }
        for (int i = 0; i < 15; ++i) {      // steps 0..29
            const int rp1 = (2 * i + 2) * 2048;
            const int rp2 = (2 * i + 3) * 2048;
            STEPROW(ghA, eA, rp1, eB, ghB);
            STEPROW(ghB, eB, rp2, eA, ghA);
        }
        STEPROW(ghA, eA, 31 * 2048, eB, ghB);   // step 30 (prefetch dummy)
        TAILROW(ghB);                           // step 31
    }

#undef TAILROW
#undef STEPROW
#undef SFMA
#undef GHBUILD
#undef PREF

    // K[511][511] = lane 63: B + s[7]
    if (l == 63) out[idx] = B + s[7];
}

__global__ void sig_reduce_kernel(const float* __restrict__ ws,
                                  float* __restrict__ out) {
    const int a = threadIdx.x;  // 128 threads
    float v = ws[a] + ws[128 + a] - 2.0f * ws[256 + a];
    #pragma unroll
    for (int off = 32; off >= 1; off >>= 1) v += __shfl_down(v, off, 64);
    __shared__ float partial[2];
    if ((a & 63) == 0) partial[a >> 6] = v;
    __syncthreads();
    if (a == 0) out[0] = (partial[0] + partial[1]) * (1.0f / 128.0f);
}

extern "C" void kernel_launch(void* const* d_in, const int* in_sizes, int n_in,
                              void* d_out, int out_size, void* d_ws, size_t ws_size,
                              hipStream_t stream) {
    const float* X = (const float*)d_in[0];
    const float* Y = (const float*)d_in[1];
    float* out = (float*)d_out;
    float* ws  = (float*)d_ws;   // 384 floats: [pair*128 + a]

    sig_pde_kernel<<<dim3(384), dim3(64), 0, stream>>>(X, Y, ws);
    sig_reduce_kernel<<<dim3(1), dim3(128), 0, stream>>>(ws, out);
}

// Round 12
// 93.186 us; speedup vs baseline: 1.0439x; 1.0439x over previous
//
#include <hip/hip_runtime.h>

#define D 16

typedef short bf16x8 __attribute__((ext_vector_type(8)));
typedef float f32x16 __attribute__((ext_vector_type(16)));
typedef float v2f __attribute__((ext_vector_type(2)));

// ---- DPP helpers (wave64), verified rounds 8-11 ----
template<int CTRL, int RMASK, bool BC>
__device__ __forceinline__ float dpp_add(float x) {
    int t = __builtin_amdgcn_update_dpp(0, __float_as_int(x), CTRL, RMASK, 0xF, BC);
    return x + __int_as_float(t);
}
__device__ __forceinline__ float wave_iscan(float x) {
    x = dpp_add<0x111, 0xF, true >(x);   // row_shr:1
    x = dpp_add<0x112, 0xF, true >(x);   // row_shr:2
    x = dpp_add<0x114, 0xF, true >(x);   // row_shr:4
    x = dpp_add<0x118, 0xF, true >(x);   // row_shr:8
    x = dpp_add<0x142, 0xA, false>(x);   // row_bcast:15
    x = dpp_add<0x143, 0xC, false>(x);   // row_bcast:31
    return x;
}

// f32 -> bf16 round-to-nearest-even
__device__ __forceinline__ short f2bf(float f) {
    unsigned u = __float_as_uint(f);
    unsigned r = u + 0x7FFFu + ((u >> 16) & 1u);
    return (short)(r >> 16);
}

// One wave per (pair,batch). Per 32-row block: 16x mfma_32x32x16_bf16 write
// (inc-1)[32][512] (f32, rot-swizzled, 0-conflict) to LDS; deferred-base scan
// (round-11 algebra) with the round-10 TOUCH pipeline discipline reinstated.
__global__ __launch_bounds__(64, 1)
void sig_pde_kernel(const float* __restrict__ X, const float* __restrict__ Y,
                    float* __restrict__ out) {
    __shared__ float sinc[32 * 512];        // 64 KB (inc-1) block, swizzled

    const int idx  = blockIdx.x;
    const int pair = idx >> 7;              // 0: XX, 1: YY, 2: XY
    const int a    = idx & 127;
    const float* Pp = (pair == 1) ? Y : X;  // row operand (dX)
    const float* Qp = (pair == 0) ? X : Y;  // col operand (dY)
    const float* prow = Pp + (size_t)a * 512 * D;
    const float* qrow = Qp + (size_t)a * 512 * D;

    const int l  = threadIdx.x;
    const int lm = l & 31;
    const int kh = l >> 5;                  // K-half of the fragment
    const int d0 = kh * 8;                  // this lane's dim offset
    const bool lane0 = (l == 0);

    // ---- B fragments: 16 column tiles of dY, resident in registers ----
    bf16x8 Bf[16];
    #pragma unroll
    for (int n = 0; n < 16; ++n) {
        int jj = 32 * n + lm - 1;
        if (jj < 0) jj = 0;                 // col 0 garbage (masked in scan)
        const float4* y1 = (const float4*)(qrow + (size_t)(jj + 1) * D + d0);
        const float4* y0 = (const float4*)(qrow + (size_t)jj * D + d0);
        float4 h1 = y1[0], h0 = y0[0], g1 = y1[1], g0 = y0[1];
        bf16x8 f;
        f[0] = f2bf(h1.x - h0.x); f[1] = f2bf(h1.y - h0.y);
        f[2] = f2bf(h1.z - h0.z); f[3] = f2bf(h1.w - h0.w);
        f[4] = f2bf(g1.x - g0.x); f[5] = f2bf(g1.y - g0.y);
        f[6] = f2bf(g1.z - g0.z); f[7] = f2bf(g1.w - g0.w);
        Bf[n] = f;
    }

    auto loadA = [&](int b) -> bf16x8 {
        int ii = 32 * b + lm - 1;
        if (ii < 0) ii = 0;                 // row 0 garbage (never scanned)
        const float4* x1 = (const float4*)(prow + (size_t)(ii + 1) * D + d0);
        const float4* x0 = (const float4*)(prow + (size_t)ii * D + d0);
        float4 h1 = x1[0], h0 = x0[0], g1 = x1[1], g0 = x0[1];
        bf16x8 f;
        f[0] = f2bf(h1.x - h0.x); f[1] = f2bf(h1.y - h0.y);
        f[2] = f2bf(h1.z - h0.z); f[3] = f2bf(h1.w - h0.w);
        f[4] = f2bf(g1.x - g0.x); f[5] = f2bf(g1.y - g0.y);
        f[6] = f2bf(g1.z - g0.z); f[7] = f2bf(g1.w - g0.w);
        return f;
    };

    const int rot = (l >> 2) & 7;           // read-side rotation (0-conflict)
    float* wbase = sinc + kh * 2048;

    int ea4[8];
    #pragma unroll
    for (int m = 0; m < 8; ++m) ea4[m] = (8 * l + ((m + rot) & 7)) * 4;

    // ---- scan state ----
    float s[8];
    #pragma unroll
    for (int m = 0; m < 8; ++m) s[m] = 0.0f;   // K[0][j] = 1 = B + 0
    float B = 1.0f;

    v2f ghA[8], ghB[8];
    float eA[8], eB[8];

    // MFMA C operand: loop-invariant -1 vector (no per-MFMA init movs)
    const f32x16 accC = {-1.f,-1.f,-1.f,-1.f,-1.f,-1.f,-1.f,-1.f,
                         -1.f,-1.f,-1.f,-1.f,-1.f,-1.f,-1.f,-1.f};

#define PREF(BUF, RB) do {                                                    \
        const char* pb_ = (const char*)sinc + (RB);                           \
        _Pragma("unroll")                                                     \
        for (int m_ = 0; m_ < 8; ++m_)                                        \
            BUF[m_] = *(const float*)(pb_ + ea4[m_]);                         \
    } while (0)

/* pin the buffer's loads: LDS returns in-order per wave, so forcing the
   last element forces all 8; placed one full row after issue -> ~0 wait */
#define TOUCH(BUF) do { float tt_ = BUF[7];                                   \
        asm volatile("" : "+v"(tt_)); BUF[7] = tt_; } while (0)

#define GHBUILD(GH, E) do {                                                   \
        float p0_ = E[0] + 1.0f;  p0_ = lane0 ? 0.0f : p0_;                   \
        float c0_ = lane0 ? 0.0f : s[0];                                      \
        GH[0][0] = p0_; GH[0][1] = c0_;                                       \
        _Pragma("unroll")                                                     \
        for (int m_ = 1; m_ < 8; ++m_) {                                      \
            v2f pc_;                                                          \
            pc_[0] = E[m_] + 1.0f;                                            \
            pc_[1] = fmaf(s[m_ - 1], E[m_], s[m_]);                          \
            GH[m_] = GH[m_ - 1] + pc_;                                        \
        }                                                                     \
    } while (0)

#define SFMA(GH) do {                                                         \
        _Pragma("unroll")                                                     \
        for (int m_ = 0; m_ < 8; ++m_)                                        \
            s[m_] = fmaf(B, GH[m_][0], GH[m_][1]);                            \
    } while (0)

// full row step: TOUCH(EN) first (issued last step -> ready), consume GHC,
// prefetch EP <- byte RP, build GHN from EN; B-update last.
#define STEPROW(GHC, EP, RP, EN, GHN) do {                                    \
        TOUCH(EN);                                                            \
        SFMA(GHC);                                                            \
        float S_ = s[7];                                                      \
        float W_ = wave_iscan(S_);      /* serial DPP chain */                \
        PREF(EP, RP);                   /* overlaps iscan */                  \
        GHBUILD(GHN, EN);               /* overlaps iscan (no W_ dep) */      \
        B = 1.0f + (W_ - S_);                                                 \
    } while (0)

#define TAILROW(GHC) do {                                                     \
        SFMA(GHC);                                                            \
        float S_ = s[7];                                                      \
        float W_ = wave_iscan(S_);                                            \
        B = 1.0f + (W_ - S_);                                                 \
    } while (0)

    bf16x8 Acur = loadA(0);

    for (int b = 0; b < 16; ++b) {
        // ---- GEMM phase: (inc-1) rows 32b..32b+31, all 512 cols ----
        #pragma unroll
        for (int n = 0; n < 16; ++n) {
            f32x16 acc = __builtin_amdgcn_mfma_f32_32x32x16_bf16(Acur, Bf[n], accC, 0, 0, 0);
            float* p = wbase + 32 * n + (lm & ~7) + (((l & 7) + n) & 7);
            #pragma unroll
            for (int r = 0; r < 16; ++r)
                p[(r & 3) * 512 + (r >> 2) * 4096] = acc[r];
        }
        if (b < 15) Acur = loadA(b + 1);    // global prefetch under the scan

        // ---- scan phase: 32 steps (block 0: dummy step resets to s=0,B=1) --
        if (b == 0) {
            #pragma unroll
            for (int m = 0; m < 8; ++m) { ghA[m][0] = 0.0f; ghA[m][1] = 0.0f; }
            PREF(eB, 2048);                 // tile row 1 (first real row)
        } else {
            PREF(eA, 0);                    // tile row 0
            PREF(eB, 2048);                 // tile row 1 (issue before use)
            GHBUILD(ghA, eA);
        }
        for (int i = 0; i < 15; ++i) {      // steps 0..29
            const int rp1 = (2 * i + 2) * 2048;
            const int rp2 = (2 * i + 3) * 2048;
            STEPROW(ghA, eA, rp1, eB, ghB);
            STEPROW(ghB, eB, rp2, eA, ghA);
        }
        STEPROW(ghA, eA, 31 * 2048, eB, ghB);   // step 30 (prefetch dummy)
        TAILROW(ghB);                           // step 31
    }

#undef TAILROW
#undef STEPROW
#undef SFMA
#undef GHBUILD
#undef TOUCH
#undef PREF

    // K[511][511] = lane 63: B + s[7]
    if (l == 63) out[idx] = B + s[7];
}

__global__ void sig_reduce_kernel(const float* __restrict__ ws,
                                  float* __restrict__ out) {
    const int a = threadIdx.x;  // 128 threads
    float v = ws[a] + ws[128 + a] - 2.0f * ws[256 + a];
    #pragma unroll
    for (int off = 32; off >= 1; off >>= 1) v += __shfl_down(v, off, 64);
    __shared__ float partial[2];
    if ((a & 63) == 0) partial[a >> 6] = v;
    __syncthreads();
    if (a == 0) out[0] = (partial[0] + partial[1]) * (1.0f / 128.0f);
}

extern "C" void kernel_launch(void* const* d_in, const int* in_sizes, int n_in,
                              void* d_out, int out_size, void* d_ws, size_t ws_size,
                              hipStream_t stream) {
    const float* X = (const float*)d_in[0];
    const float* Y = (const float*)d_in[1];
    float* out = (float*)d_out;
    float* ws  = (float*)d_ws;   // 384 floats: [pair*128 + a]

    sig_pde_kernel<<<dim3(384), dim3(64), 0, stream>>>(X, Y, ws);
    sig_reduce_kernel<<<dim3(1), dim3(128), 0, stream>>>(ws, out);
}